// Round 26
// baseline (365.444 us; speedup 1.0000x reference)
//
#include <hip/hip_runtime.h>
#include <hip/hip_bf16.h>
#include <stdint.h>

#define M_DIM 8192
#define N_DIM 4096
#define K_DIM 4096
#define NNZ   1600000

typedef __attribute__((ext_vector_type(8))) short bf16x8;
typedef __attribute__((ext_vector_type(4))) float f32x4;

// workspace layout (bytes)
static const size_t WF32_OFF  = 0;
static const size_t WBF16_OFF = 64ull << 20;
static const size_t XB_OFF    = 96ull << 20;
static const size_t WS_NEED   = 160ull << 20;

__device__ __forceinline__ unsigned short f2bf(float f) {
    union { float f; uint32_t u; } a; a.f = f;
    uint32_t u = a.u;
    uint32_t r = (u + 0x7FFFu + ((u >> 16) & 1u)) >> 16;   // RNE
    return (unsigned short)r;
}

__global__ void scatter_kernel(const int* __restrict__ idx,
                               const float* __restrict__ vals,
                               float* __restrict__ W) {
    int t = blockIdx.x * blockDim.x + threadIdx.x;
    if (t < NNZ) {
        int2 rc = ((const int2*)idx)[t];
        atomicAdd(&W[(size_t)rc.x * K_DIM + rc.y], vals[t]);
    }
}

// grid-stride convert of BOTH W (n4W quads) and x (rest) fp32 -> bf16.
// 2048 blocks (guideline 11): measured best aux config (r18-r25).
__global__ void convert_both_kernel(const float* __restrict__ W,
                                    const float* __restrict__ x,
                                    unsigned short* __restrict__ Wb,
                                    unsigned short* __restrict__ xb,
                                    int n4W, int n4T) {
    const int stride = gridDim.x * blockDim.x;
    for (int t = blockIdx.x * blockDim.x + threadIdx.x; t < n4T; t += stride) {
        const float* src; unsigned short* dst; int i;
        if (t < n4W) { src = W; dst = Wb; i = t; }
        else         { src = x; dst = xb; i = t - n4W; }
        float4 v = ((const float4*)src)[i];
        ushort4 o;
        o.x = f2bf(v.x); o.y = f2bf(v.y); o.z = f2bf(v.z); o.w = f2bf(v.w);
        ((ushort4*)dst)[i] = o;
    }
}

// ---------------------------------------------------------------------------
// 256x256 bf16 MFMA GEMM, BK=64, 8 waves (2Mx4N), per-wave 128x64 out,
// 16x16x32 MFMA. Cluster-ahead read schedule — BEST MEASURED GEMM of the
// session (240-250 us, MfmaUtil 45-49%, 0 bank conflicts, no spill;
// confirmed stable across r16/r18/r20-r25).
// Family floor: LDS pipe (~2300 cyc/tile, traffic-minimal at WM+WN=6) +
// MFMA pipe (~2480 cyc/tile) run near-serial; refuted levers: manual-pin
// phase schedules (r2/r4), cross-tile read-ahead (r7 spill), k-slot
// ping-pong (r12 spill), 2 blocks/CU (r17), 32x32 MFMA (r6 — >=4-way bank
// conflict is unavoidable for b128x32-lane reads under gload_lds-linear
// layout), fp8 (error budget: bf16 absmax 0.0156 x ~8-16 > 0.0475 thr).
//   R0: read bLo(4)+aLo(8)+bHi(4) ; MFMA Q00 ; stage B(t+1)g23 -> c^1
//   BAR1 ; R1: stage B(t+2)g01 -> c ; read aHi(8) ; MFMA Q01
//   BAR2 ; R2: stage A(t+2) -> c ; MFMA Q11 ; MFMA Q10
//   boundary: vmcnt(6); BAR   (t==NT-2: vmcnt(0); t==NT-1: none)
// LDS swizzle (0-conflict, measured): 16B slot u of row r at u^(r&7);
// inverse-swizzled global source keeps gload_lds dest linear (rule 21).
// ---------------------------------------------------------------------------
#define GLOAD16(gp, lp) __builtin_amdgcn_global_load_lds( \
    (const __attribute__((address_space(1))) void*)(gp),  \
    (__attribute__((address_space(3))) void*)(lp), 16, 0, 0)
#define VMCNT(n)   asm volatile("s_waitcnt vmcnt(" #n ")" ::: "memory")
#define BAR()    __builtin_amdgcn_s_barrier()

// frag read from 256x64 swizzled tile: row r, k-slot kk in {0,1}
#define FRAG(T, r, kk) \
    (*(const bf16x8*)&(T)[(r) * 64 + (((((kk) << 2) + l4) ^ ((r) & 7)) << 3)])

// stage one 64-row group g (0..3) of a 256x64 tile: 1 gload x 512 thr x 16B
#define STAGE_AG(buf, tt, g) \
    GLOAD16(Ab + (size_t)((g) * 64 + rbase) * K_DIM + (size_t)(tt) * 64 + cs, \
            &sA[buf][(g) * 4096 + wid * 512])
#define STAGE_BG(buf, tt, g) \
    GLOAD16(Bb + (size_t)((g) * 64 + rbase) * K_DIM + (size_t)(tt) * 64 + cs, \
            &sB[buf][(g) * 4096 + wid * 512])

__global__ __launch_bounds__(512, 2) void gemm256_v9(
        const __hip_bfloat16* __restrict__ A,   // M x K
        const __hip_bfloat16* __restrict__ B,   // N x K
        float* __restrict__ C)                  // M x N
{
    __shared__ __align__(16) __hip_bfloat16 sA[2][256 * 64];
    __shared__ __align__(16) __hip_bfloat16 sB[2][256 * 64];

    const int tid  = threadIdx.x;
    const int lane = tid & 63;
    const int wid  = tid >> 6;
    const int wr   = wid >> 2;      // 0..1  (128-row half of A-tile)
    const int wc   = wid & 3;       // 0..3  (64-col slice of B-tile)
    const int l15  = lane & 15, l4 = lane >> 4;

    // XCD-aware bijective swizzle (nwg = 512, %8 == 0)
    const int bid = blockIdx.x;
    const int swz = (bid & 7) * 64 + (bid >> 3);
    const int m0  = (swz >> 4) * 256;   // 32 m-tiles
    const int n0  = (swz & 15) * 256;   // 16 n-tiles

    // staging geometry: row-in-group = tid>>3; 16B col-slot u = tid&7;
    // inverse-swizzled source col = (u ^ (row&7))*8
    const int rbase = tid >> 3;
    const int cs    = ((tid & 7) ^ (rbase & 7)) << 3;

    const __hip_bfloat16* Ab = A + (size_t)m0 * K_DIM;
    const __hip_bfloat16* Bb = B + (size_t)n0 * K_DIM;

    // acc quadrants: m 0..3 = mLo, 4..7 = mHi; n 0..1 = nLo, 2..3 = nHi
    f32x4 acc[8][4] = {};

    // ---- prologue (issue order matches steady state):
    //   tile0 full (8) ; B(1)g01 (2) ; A(1) full (4)
    STAGE_AG(0, 0, 0); STAGE_AG(0, 0, 1); STAGE_AG(0, 0, 2); STAGE_AG(0, 0, 3);
    STAGE_BG(0, 0, 0); STAGE_BG(0, 0, 1); STAGE_BG(0, 0, 2); STAGE_BG(0, 0, 3);
    STAGE_BG(1, 1, 0); STAGE_BG(1, 1, 1);
    STAGE_AG(1, 1, 0); STAGE_AG(1, 1, 1); STAGE_AG(1, 1, 2); STAGE_AG(1, 1, 3);
    VMCNT(6);          // tile 0 landed; {B(1)g01 x2, A(1) x4} in flight
    BAR();

    const int NT = K_DIM / 64;      // 64
    #pragma unroll 2
    for (int t = 0; t < NT; ++t) {
        const int c = t & 1;
        const __hip_bfloat16* TA = sA[c];
        const __hip_bfloat16* TB = sB[c];

        bf16x8 aLo[4][2], aHi[4][2], bLo[2][2], bHi[2][2];

        // ================= R0 =================
        #pragma unroll
        for (int n = 0; n < 2; ++n) bLo[n][0] = FRAG(TB, wc * 64 + n * 16 + l15, 0);
        #pragma unroll
        for (int m = 0; m < 4; ++m) aLo[m][0] = FRAG(TA, wr * 128 + m * 16 + l15, 0);
        #pragma unroll
        for (int n = 0; n < 2; ++n) bLo[n][1] = FRAG(TB, wc * 64 + n * 16 + l15, 1);
        #pragma unroll
        for (int m = 0; m < 4; ++m) aLo[m][1] = FRAG(TA, wr * 128 + m * 16 + l15, 1);
        #pragma unroll
        for (int n = 0; n < 2; ++n) {
            const int r = wc * 64 + 32 + n * 16 + l15;
            bHi[n][0] = FRAG(TB, r, 0);
            bHi[n][1] = FRAG(TB, r, 1);
        }
        __builtin_amdgcn_s_setprio(1);
        #pragma unroll
        for (int k = 0; k < 2; ++k)
            #pragma unroll
            for (int m = 0; m < 4; ++m)
                #pragma unroll
                for (int n = 0; n < 2; ++n)
                    acc[m][n] = __builtin_amdgcn_mfma_f32_16x16x32_bf16(
                                    aLo[m][k], bLo[n][k], acc[m][n], 0, 0, 0);
        __builtin_amdgcn_s_setprio(0);
        if (t + 1 < NT) { STAGE_BG(c ^ 1, t + 1, 2); STAGE_BG(c ^ 1, t + 1, 3); }
        BAR();   // BAR1: all B-reads (bLo,bHi) + aLo of buf c complete

        // ================= R1 =================
        if (t + 2 < NT) { STAGE_BG(c, t + 2, 0); STAGE_BG(c, t + 2, 1); }
        #pragma unroll
        for (int m = 0; m < 4; ++m) {
            const int r = wr * 128 + 64 + m * 16 + l15;
            aHi[m][0] = FRAG(TA, r, 0);
            aHi[m][1] = FRAG(TA, r, 1);
        }
        __builtin_amdgcn_s_setprio(1);
        #pragma unroll
        for (int k = 0; k < 2; ++k)
            #pragma unroll
            for (int m = 0; m < 4; ++m)
                #pragma unroll
                for (int n = 0; n < 2; ++n)
                    acc[m][2 + n] = __builtin_amdgcn_mfma_f32_16x16x32_bf16(
                                    aLo[m][k], bHi[n][k], acc[m][2 + n], 0, 0, 0);
        __builtin_amdgcn_s_setprio(0);
        BAR();   // BAR2: all A-reads (aLo,aHi) of buf c complete

        // ================= R2 =================
        if (t + 2 < NT) {
            STAGE_AG(c, t + 2, 0); STAGE_AG(c, t + 2, 1);
            STAGE_AG(c, t + 2, 2); STAGE_AG(c, t + 2, 3);
        }
        __builtin_amdgcn_s_setprio(1);
        #pragma unroll
        for (int k = 0; k < 2; ++k)
            #pragma unroll
            for (int m = 0; m < 4; ++m)
                #pragma unroll
                for (int n = 0; n < 2; ++n)
                    acc[4 + m][2 + n] = __builtin_amdgcn_mfma_f32_16x16x32_bf16(
                                    aHi[m][k], bHi[n][k], acc[4 + m][2 + n], 0, 0, 0);
        #pragma unroll
        for (int k = 0; k < 2; ++k)
            #pragma unroll
            for (int m = 0; m < 4; ++m)
                #pragma unroll
                for (int n = 0; n < 2; ++n)
                    acc[4 + m][n] = __builtin_amdgcn_mfma_f32_16x16x32_bf16(
                                    aHi[m][k], bLo[n][k], acc[4 + m][n], 0, 0, 0);
        __builtin_amdgcn_s_setprio(0);

        // ---------- K-tile boundary ----------
        if (t < NT - 2) {
            VMCNT(6);       // drains all of tile t+1; 6 loads of t+2 in flight
            BAR();
        } else if (t == NT - 2) {
            VMCNT(0);       // tail: drain B(NT-1)g23
            BAR();
        }
        // t == NT-1: registers only; fall through to epilogue
    }

    // ---- epilogue: ReLU + fp32 store ----
    const int row_base = m0 + wr * 128;
    const int col_base = n0 + wc * 64;
    #pragma unroll
    for (int m = 0; m < 8; ++m)
        #pragma unroll
        for (int n = 0; n < 4; ++n) {
            const f32x4 v = acc[m][n];
            const int col = col_base + n * 16 + l15;
            #pragma unroll
            for (int j = 0; j < 4; ++j) {
                const int row = row_base + m * 16 + l4 * 4 + j;
                C[(size_t)row * N_DIM + col] = fmaxf(v[j], 0.0f);
            }
        }
}

// ---------------------------------------------------------------------------
// fp32 fallback GEMM (only if ws_size < 160MB)
// ---------------------------------------------------------------------------
__global__ void gemm_f32_fallback(const float* __restrict__ A,
                                  const float* __restrict__ W,
                                  float* __restrict__ C) {
    __shared__ float As[64][17];
    __shared__ float Bs[64][17];
    const int tx = threadIdx.x & 15, ty = threadIdx.x >> 4;
    const int m0 = blockIdx.y * 64, n0 = blockIdx.x * 64;
    float acc[4][4] = {};
    for (int kt = 0; kt < K_DIM; kt += 16) {
        #pragma unroll
        for (int i = 0; i < 4; ++i) {
            int e = threadIdx.x + i * 256;
            int r = e >> 4, k = e & 15;
            As[r][k] = A[(size_t)(m0 + r) * K_DIM + kt + k];
            Bs[r][k] = W[(size_t)(n0 + r) * K_DIM + kt + k];
        }
        __syncthreads();
        #pragma unroll
        for (int k = 0; k < 16; ++k) {
            float av[4], bv[4];
            #pragma unroll
            for (int i = 0; i < 4; ++i) av[i] = As[ty * 4 + i][k];
            #pragma unroll
            for (int i = 0; i < 4; ++i) bv[i] = Bs[tx * 4 + i][k];
            #pragma unroll
            for (int i = 0; i < 4; ++i)
                #pragma unroll
                for (int j = 0; j < 4; ++j) acc[i][j] += av[i] * bv[j];
        }
        __syncthreads();
    }
    #pragma unroll
    for (int i = 0; i < 4; ++i)
        #pragma unroll
        for (int j = 0; j < 4; ++j)
            C[(size_t)(m0 + ty * 4 + i) * N_DIM + n0 + tx * 4 + j] =
                fmaxf(acc[i][j], 0.0f);
}

extern "C" void kernel_launch(void* const* d_in, const int* in_sizes, int n_in,
                              void* d_out, int out_size, void* d_ws, size_t ws_size,
                              hipStream_t stream) {
    const float* x       = (const float*)d_in[0];
    const int*   indices = (const int*)d_in[1];
    const float* values  = (const float*)d_in[2];
    float*       out     = (float*)d_out;

    float* Wf = (float*)((char*)d_ws + WF32_OFF);

    // 1. zero + scatter-build W (fp32, duplicates accumulate)
    hipMemsetAsync(Wf, 0, (size_t)N_DIM * K_DIM * sizeof(float), stream);
    scatter_kernel<<<(NNZ + 255) / 256, 256, 0, stream>>>(indices, values, Wf);

    if (ws_size >= WS_NEED) {
        unsigned short* Wb = (unsigned short*)((char*)d_ws + WBF16_OFF);
        unsigned short* xb = (unsigned short*)((char*)d_ws + XB_OFF);

        // 2. fused fp32 -> bf16 conversion (W then x), grid-stride @2048 blocks
        const int n4W = (N_DIM * K_DIM) / 4;
        const int n4T = n4W + (M_DIM * K_DIM) / 4;
        convert_both_kernel<<<2048, 256, 0, stream>>>(Wf, x, Wb, xb, n4W, n4T);

        // 3. 256^2 cluster-ahead bf16 MFMA GEMM + ReLU (session best)
        gemm256_v9<<<(M_DIM / 256) * (N_DIM / 256), 512, 0, stream>>>(
            (const __hip_bfloat16*)xb, (const __hip_bfloat16*)Wb, out);
    } else {
        gemm_f32_fallback<<<dim3(N_DIM / 64, M_DIM / 64), 256, 0, stream>>>(
            x, Wf, out);
    }
}

// Round 27
// 352.395 us; speedup vs baseline: 1.0370x; 1.0370x over previous
//
#include <hip/hip_runtime.h>
#include <hip/hip_bf16.h>
#include <stdint.h>

#define M_DIM 8192
#define N_DIM 4096
#define K_DIM 4096
#define NNZ   1600000

typedef __attribute__((ext_vector_type(8))) short bf16x8;
typedef __attribute__((ext_vector_type(4))) float f32x4;

// workspace layout (bytes)
static const size_t WF32_OFF  = 0;
static const size_t WBF16_OFF = 64ull << 20;
static const size_t XB_OFF    = 96ull << 20;
static const size_t WS_NEED   = 160ull << 20;

__device__ __forceinline__ unsigned short f2bf(float f) {
    union { float f; uint32_t u; } a; a.f = f;
    uint32_t u = a.u;
    uint32_t r = (u + 0x7FFFu + ((u >> 16) & 1u)) >> 16;   // RNE
    return (unsigned short)r;
}

__global__ void scatter_kernel(const int* __restrict__ idx,
                               const float* __restrict__ vals,
                               float* __restrict__ W) {
    int t = blockIdx.x * blockDim.x + threadIdx.x;
    if (t < NNZ) {
        int2 rc = ((const int2*)idx)[t];
        atomicAdd(&W[(size_t)rc.x * K_DIM + rc.y], vals[t]);
    }
}

// grid-stride convert of BOTH W (n4W quads) and x (rest) fp32 -> bf16.
// 2048 blocks (guideline 11): measured best aux config (r18-r26).
__global__ void convert_both_kernel(const float* __restrict__ W,
                                    const float* __restrict__ x,
                                    unsigned short* __restrict__ Wb,
                                    unsigned short* __restrict__ xb,
                                    int n4W, int n4T) {
    const int stride = gridDim.x * blockDim.x;
    for (int t = blockIdx.x * blockDim.x + threadIdx.x; t < n4T; t += stride) {
        const float* src; unsigned short* dst; int i;
        if (t < n4W) { src = W; dst = Wb; i = t; }
        else         { src = x; dst = xb; i = t - n4W; }
        float4 v = ((const float4*)src)[i];
        ushort4 o;
        o.x = f2bf(v.x); o.y = f2bf(v.y); o.z = f2bf(v.z); o.w = f2bf(v.w);
        ((ushort4*)dst)[i] = o;
    }
}

// ---------------------------------------------------------------------------
// 256x256 bf16 MFMA GEMM, BK=64, 8 waves (2Mx4N), per-wave 128x64 out,
// 16x16x32 MFMA. Cluster-ahead read schedule — BEST MEASURED GEMM of the
// session (240-250 us, MfmaUtil 45-49%, 0 bank conflicts, no spill;
// confirmed stable across r16/r18/r20-r26).
// Family floor: LDS pipe (~2300 cyc/tile, traffic-minimal at WM+WN=6) +
// MFMA pipe (~2480 cyc/tile) run near-serial; refuted levers: manual-pin
// phase schedules (r2/r4), cross-tile read-ahead (r7 spill), k-slot
// ping-pong (r12 spill), 2 blocks/CU (r17), 32x32 MFMA (r6 — >=4-way bank
// conflict is unavoidable for b128x32-lane reads under gload_lds-linear
// layout), fp8 (error budget: bf16 absmax 0.0156 x ~8-16 > 0.0475 thr).
//   R0: read bLo(4)+aLo(8)+bHi(4) ; MFMA Q00 ; stage B(t+1)g23 -> c^1
//   BAR1 ; R1: stage B(t+2)g01 -> c ; read aHi(8) ; MFMA Q01
//   BAR2 ; R2: stage A(t+2) -> c ; MFMA Q11 ; MFMA Q10
//   boundary: vmcnt(6); BAR   (t==NT-2: vmcnt(0); t==NT-1: none)
// LDS swizzle (0-conflict, measured): 16B slot u of row r at u^(r&7);
// inverse-swizzled global source keeps gload_lds dest linear (rule 21).
// ---------------------------------------------------------------------------
#define GLOAD16(gp, lp) __builtin_amdgcn_global_load_lds( \
    (const __attribute__((address_space(1))) void*)(gp),  \
    (__attribute__((address_space(3))) void*)(lp), 16, 0, 0)
#define VMCNT(n)   asm volatile("s_waitcnt vmcnt(" #n ")" ::: "memory")
#define BAR()    __builtin_amdgcn_s_barrier()

// frag read from 256x64 swizzled tile: row r, k-slot kk in {0,1}
#define FRAG(T, r, kk) \
    (*(const bf16x8*)&(T)[(r) * 64 + (((((kk) << 2) + l4) ^ ((r) & 7)) << 3)])

// stage one 64-row group g (0..3) of a 256x64 tile: 1 gload x 512 thr x 16B
#define STAGE_AG(buf, tt, g) \
    GLOAD16(Ab + (size_t)((g) * 64 + rbase) * K_DIM + (size_t)(tt) * 64 + cs, \
            &sA[buf][(g) * 4096 + wid * 512])
#define STAGE_BG(buf, tt, g) \
    GLOAD16(Bb + (size_t)((g) * 64 + rbase) * K_DIM + (size_t)(tt) * 64 + cs, \
            &sB[buf][(g) * 4096 + wid * 512])

__global__ __launch_bounds__(512, 2) void gemm256_v9(
        const __hip_bfloat16* __restrict__ A,   // M x K
        const __hip_bfloat16* __restrict__ B,   // N x K
        float* __restrict__ C)                  // M x N
{
    __shared__ __align__(16) __hip_bfloat16 sA[2][256 * 64];
    __shared__ __align__(16) __hip_bfloat16 sB[2][256 * 64];

    const int tid  = threadIdx.x;
    const int lane = tid & 63;
    const int wid  = tid >> 6;
    const int wr   = wid >> 2;      // 0..1  (128-row half of A-tile)
    const int wc   = wid & 3;       // 0..3  (64-col slice of B-tile)
    const int l15  = lane & 15, l4 = lane >> 4;

    // XCD-aware bijective swizzle (nwg = 512, %8 == 0)
    const int bid = blockIdx.x;
    const int swz = (bid & 7) * 64 + (bid >> 3);
    const int m0  = (swz >> 4) * 256;   // 32 m-tiles
    const int n0  = (swz & 15) * 256;   // 16 n-tiles

    // staging geometry: row-in-group = tid>>3; 16B col-slot u = tid&7;
    // inverse-swizzled source col = (u ^ (row&7))*8
    const int rbase = tid >> 3;
    const int cs    = ((tid & 7) ^ (rbase & 7)) << 3;

    const __hip_bfloat16* Ab = A + (size_t)m0 * K_DIM;
    const __hip_bfloat16* Bb = B + (size_t)n0 * K_DIM;

    // acc quadrants: m 0..3 = mLo, 4..7 = mHi; n 0..1 = nLo, 2..3 = nHi
    f32x4 acc[8][4] = {};

    // ---- prologue (issue order matches steady state):
    //   tile0 full (8) ; B(1)g01 (2) ; A(1) full (4)
    STAGE_AG(0, 0, 0); STAGE_AG(0, 0, 1); STAGE_AG(0, 0, 2); STAGE_AG(0, 0, 3);
    STAGE_BG(0, 0, 0); STAGE_BG(0, 0, 1); STAGE_BG(0, 0, 2); STAGE_BG(0, 0, 3);
    STAGE_BG(1, 1, 0); STAGE_BG(1, 1, 1);
    STAGE_AG(1, 1, 0); STAGE_AG(1, 1, 1); STAGE_AG(1, 1, 2); STAGE_AG(1, 1, 3);
    VMCNT(6);          // tile 0 landed; {B(1)g01 x2, A(1) x4} in flight
    BAR();

    const int NT = K_DIM / 64;      // 64
    #pragma unroll 2
    for (int t = 0; t < NT; ++t) {
        const int c = t & 1;
        const __hip_bfloat16* TA = sA[c];
        const __hip_bfloat16* TB = sB[c];

        bf16x8 aLo[4][2], aHi[4][2], bLo[2][2], bHi[2][2];

        // ================= R0 =================
        #pragma unroll
        for (int n = 0; n < 2; ++n) bLo[n][0] = FRAG(TB, wc * 64 + n * 16 + l15, 0);
        #pragma unroll
        for (int m = 0; m < 4; ++m) aLo[m][0] = FRAG(TA, wr * 128 + m * 16 + l15, 0);
        #pragma unroll
        for (int n = 0; n < 2; ++n) bLo[n][1] = FRAG(TB, wc * 64 + n * 16 + l15, 1);
        #pragma unroll
        for (int m = 0; m < 4; ++m) aLo[m][1] = FRAG(TA, wr * 128 + m * 16 + l15, 1);
        #pragma unroll
        for (int n = 0; n < 2; ++n) {
            const int r = wc * 64 + 32 + n * 16 + l15;
            bHi[n][0] = FRAG(TB, r, 0);
            bHi[n][1] = FRAG(TB, r, 1);
        }
        __builtin_amdgcn_s_setprio(1);
        #pragma unroll
        for (int k = 0; k < 2; ++k)
            #pragma unroll
            for (int m = 0; m < 4; ++m)
                #pragma unroll
                for (int n = 0; n < 2; ++n)
                    acc[m][n] = __builtin_amdgcn_mfma_f32_16x16x32_bf16(
                                    aLo[m][k], bLo[n][k], acc[m][n], 0, 0, 0);
        __builtin_amdgcn_s_setprio(0);
        if (t + 1 < NT) { STAGE_BG(c ^ 1, t + 1, 2); STAGE_BG(c ^ 1, t + 1, 3); }
        BAR();   // BAR1: all B-reads (bLo,bHi) + aLo of buf c complete

        // ================= R1 =================
        if (t + 2 < NT) { STAGE_BG(c, t + 2, 0); STAGE_BG(c, t + 2, 1); }
        #pragma unroll
        for (int m = 0; m < 4; ++m) {
            const int r = wr * 128 + 64 + m * 16 + l15;
            aHi[m][0] = FRAG(TA, r, 0);
            aHi[m][1] = FRAG(TA, r, 1);
        }
        __builtin_amdgcn_s_setprio(1);
        #pragma unroll
        for (int k = 0; k < 2; ++k)
            #pragma unroll
            for (int m = 0; m < 4; ++m)
                #pragma unroll
                for (int n = 0; n < 2; ++n)
                    acc[m][2 + n] = __builtin_amdgcn_mfma_f32_16x16x32_bf16(
                                    aLo[m][k], bHi[n][k], acc[m][2 + n], 0, 0, 0);
        __builtin_amdgcn_s_setprio(0);
        BAR();   // BAR2: all A-reads (aLo,aHi) of buf c complete

        // ================= R2 =================
        if (t + 2 < NT) {
            STAGE_AG(c, t + 2, 0); STAGE_AG(c, t + 2, 1);
            STAGE_AG(c, t + 2, 2); STAGE_AG(c, t + 2, 3);
        }
        __builtin_amdgcn_s_setprio(1);
        #pragma unroll
        for (int k = 0; k < 2; ++k)
            #pragma unroll
            for (int m = 0; m < 4; ++m)
                #pragma unroll
                for (int n = 0; n < 2; ++n)
                    acc[4 + m][2 + n] = __builtin_amdgcn_mfma_f32_16x16x32_bf16(
                                    aHi[m][k], bHi[n][k], acc[4 + m][2 + n], 0, 0, 0);
        #pragma unroll
        for (int k = 0; k < 2; ++k)
            #pragma unroll
            for (int m = 0; m < 4; ++m)
                #pragma unroll
                for (int n = 0; n < 2; ++n)
                    acc[4 + m][n] = __builtin_amdgcn_mfma_f32_16x16x32_bf16(
                                    aHi[m][k], bLo[n][k], acc[4 + m][n], 0, 0, 0);
        __builtin_amdgcn_s_setprio(0);

        // ---------- K-tile boundary ----------
        if (t < NT - 2) {
            VMCNT(6);       // drains all of tile t+1; 6 loads of t+2 in flight
            BAR();
        } else if (t == NT - 2) {
            VMCNT(0);       // tail: drain B(NT-1)g23
            BAR();
        }
        // t == NT-1: registers only; fall through to epilogue
    }

    // ---- epilogue: ReLU + fp32 store ----
    const int row_base = m0 + wr * 128;
    const int col_base = n0 + wc * 64;
    #pragma unroll
    for (int m = 0; m < 8; ++m)
        #pragma unroll
        for (int n = 0; n < 4; ++n) {
            const f32x4 v = acc[m][n];
            const int col = col_base + n * 16 + l15;
            #pragma unroll
            for (int j = 0; j < 4; ++j) {
                const int row = row_base + m * 16 + l4 * 4 + j;
                C[(size_t)row * N_DIM + col] = fmaxf(v[j], 0.0f);
            }
        }
}

// ---------------------------------------------------------------------------
// fp32 fallback GEMM (only if ws_size < 160MB)
// ---------------------------------------------------------------------------
__global__ void gemm_f32_fallback(const float* __restrict__ A,
                                  const float* __restrict__ W,
                                  float* __restrict__ C) {
    __shared__ float As[64][17];
    __shared__ float Bs[64][17];
    const int tx = threadIdx.x & 15, ty = threadIdx.x >> 4;
    const int m0 = blockIdx.y * 64, n0 = blockIdx.x * 64;
    float acc[4][4] = {};
    for (int kt = 0; kt < K_DIM; kt += 16) {
        #pragma unroll
        for (int i = 0; i < 4; ++i) {
            int e = threadIdx.x + i * 256;
            int r = e >> 4, k = e & 15;
            As[r][k] = A[(size_t)(m0 + r) * K_DIM + kt + k];
            Bs[r][k] = W[(size_t)(n0 + r) * K_DIM + kt + k];
        }
        __syncthreads();
        #pragma unroll
        for (int k = 0; k < 16; ++k) {
            float av[4], bv[4];
            #pragma unroll
            for (int i = 0; i < 4; ++i) av[i] = As[ty * 4 + i][k];
            #pragma unroll
            for (int i = 0; i < 4; ++i) bv[i] = Bs[tx * 4 + i][k];
            #pragma unroll
            for (int i = 0; i < 4; ++i)
                #pragma unroll
                for (int j = 0; j < 4; ++j) acc[i][j] += av[i] * bv[j];
        }
        __syncthreads();
    }
    #pragma unroll
    for (int i = 0; i < 4; ++i)
        #pragma unroll
        for (int j = 0; j < 4; ++j)
            C[(size_t)(m0 + ty * 4 + i) * N_DIM + n0 + tx * 4 + j] =
                fmaxf(acc[i][j], 0.0f);
}

extern "C" void kernel_launch(void* const* d_in, const int* in_sizes, int n_in,
                              void* d_out, int out_size, void* d_ws, size_t ws_size,
                              hipStream_t stream) {
    const float* x       = (const float*)d_in[0];
    const int*   indices = (const int*)d_in[1];
    const float* values  = (const float*)d_in[2];
    float*       out     = (float*)d_out;

    float* Wf = (float*)((char*)d_ws + WF32_OFF);

    // 1. zero + scatter-build W (fp32, duplicates accumulate)
    hipMemsetAsync(Wf, 0, (size_t)N_DIM * K_DIM * sizeof(float), stream);
    scatter_kernel<<<(NNZ + 255) / 256, 256, 0, stream>>>(indices, values, Wf);

    if (ws_size >= WS_NEED) {
        unsigned short* Wb = (unsigned short*)((char*)d_ws + WBF16_OFF);
        unsigned short* xb = (unsigned short*)((char*)d_ws + XB_OFF);

        // 2. fused fp32 -> bf16 conversion (W then x), grid-stride @2048 blocks
        const int n4W = (N_DIM * K_DIM) / 4;
        const int n4T = n4W + (M_DIM * K_DIM) / 4;
        convert_both_kernel<<<2048, 256, 0, stream>>>(Wf, x, Wb, xb, n4W, n4T);

        // 3. 256^2 cluster-ahead bf16 MFMA GEMM + ReLU (session best)
        gemm256_v9<<<(M_DIM / 256) * (N_DIM / 256), 512, 0, stream>>>(
            (const __hip_bfloat16*)xb, (const __hip_bfloat16*)Wb, out);
    } else {
        gemm_f32_fallback<<<dim3(N_DIM / 64, M_DIM / 64), 256, 0, stream>>>(
            x, Wf, out);
    }
}

// Round 28
// 350.724 us; speedup vs baseline: 1.0420x; 1.0048x over previous
//
#include <hip/hip_runtime.h>
#include <hip/hip_bf16.h>
#include <stdint.h>

#define M_DIM 8192
#define N_DIM 4096
#define K_DIM 4096
#define NNZ   1600000

typedef __attribute__((ext_vector_type(8))) short bf16x8;
typedef __attribute__((ext_vector_type(4))) float f32x4;

// workspace layout (bytes)
static const size_t WF32_OFF  = 0;
static const size_t WBF16_OFF = 64ull << 20;
static const size_t XB_OFF    = 96ull << 20;
static const size_t WS_NEED   = 160ull << 20;

__device__ __forceinline__ unsigned short f2bf(float f) {
    union { float f; uint32_t u; } a; a.f = f;
    uint32_t u = a.u;
    uint32_t r = (u + 0x7FFFu + ((u >> 16) & 1u)) >> 16;   // RNE
    return (unsigned short)r;
}

__global__ void scatter_kernel(const int* __restrict__ idx,
                               const float* __restrict__ vals,
                               float* __restrict__ W) {
    int t = blockIdx.x * blockDim.x + threadIdx.x;
    if (t < NNZ) {
        int2 rc = ((const int2*)idx)[t];
        atomicAdd(&W[(size_t)rc.x * K_DIM + rc.y], vals[t]);
    }
}

// grid-stride convert of BOTH W (n4W quads) and x (rest) fp32 -> bf16.
// 2048 blocks (guideline 11): measured best aux config (r18-r27).
__global__ void convert_both_kernel(const float* __restrict__ W,
                                    const float* __restrict__ x,
                                    unsigned short* __restrict__ Wb,
                                    unsigned short* __restrict__ xb,
                                    int n4W, int n4T) {
    const int stride = gridDim.x * blockDim.x;
    for (int t = blockIdx.x * blockDim.x + threadIdx.x; t < n4T; t += stride) {
        const float* src; unsigned short* dst; int i;
        if (t < n4W) { src = W; dst = Wb; i = t; }
        else         { src = x; dst = xb; i = t - n4W; }
        float4 v = ((const float4*)src)[i];
        ushort4 o;
        o.x = f2bf(v.x); o.y = f2bf(v.y); o.z = f2bf(v.z); o.w = f2bf(v.w);
        ((ushort4*)dst)[i] = o;
    }
}

// ---------------------------------------------------------------------------
// 256x256 bf16 MFMA GEMM, BK=64, 8 waves (2Mx4N), per-wave 128x64 out,
// 16x16x32 MFMA. Cluster-ahead read schedule — BEST MEASURED GEMM of the
// session (240-250 us, MfmaUtil 45-49%, 0 bank conflicts, no spill;
// confirmed stable across r16/r18/r20-r27).
// Family floor: LDS pipe (~2300 cyc/tile, traffic-minimal at WM+WN=6) +
// MFMA pipe (~2480 cyc/tile) run near-serial; refuted levers: manual-pin
// phase schedules (r2/r4), cross-tile read-ahead (r7 spill), k-slot
// ping-pong (r12 spill), 2 blocks/CU (r17), 32x32 MFMA (r6 — >=4-way bank
// conflict is unavoidable for b128x32-lane reads under gload_lds-linear
// layout), fp8 (error budget: bf16 absmax 0.0156 x ~8-16 > 0.0475 thr).
//   R0: read bLo(4)+aLo(8)+bHi(4) ; MFMA Q00 ; stage B(t+1)g23 -> c^1
//   BAR1 ; R1: stage B(t+2)g01 -> c ; read aHi(8) ; MFMA Q01
//   BAR2 ; R2: stage A(t+2) -> c ; MFMA Q11 ; MFMA Q10
//   boundary: vmcnt(6); BAR   (t==NT-2: vmcnt(0); t==NT-1: none)
// LDS swizzle (0-conflict, measured): 16B slot u of row r at u^(r&7);
// inverse-swizzled global source keeps gload_lds dest linear (rule 21).
// ---------------------------------------------------------------------------
#define GLOAD16(gp, lp) __builtin_amdgcn_global_load_lds( \
    (const __attribute__((address_space(1))) void*)(gp),  \
    (__attribute__((address_space(3))) void*)(lp), 16, 0, 0)
#define VMCNT(n)   asm volatile("s_waitcnt vmcnt(" #n ")" ::: "memory")
#define BAR()    __builtin_amdgcn_s_barrier()

// frag read from 256x64 swizzled tile: row r, k-slot kk in {0,1}
#define FRAG(T, r, kk) \
    (*(const bf16x8*)&(T)[(r) * 64 + (((((kk) << 2) + l4) ^ ((r) & 7)) << 3)])

// stage one 64-row group g (0..3) of a 256x64 tile: 1 gload x 512 thr x 16B
#define STAGE_AG(buf, tt, g) \
    GLOAD16(Ab + (size_t)((g) * 64 + rbase) * K_DIM + (size_t)(tt) * 64 + cs, \
            &sA[buf][(g) * 4096 + wid * 512])
#define STAGE_BG(buf, tt, g) \
    GLOAD16(Bb + (size_t)((g) * 64 + rbase) * K_DIM + (size_t)(tt) * 64 + cs, \
            &sB[buf][(g) * 4096 + wid * 512])

__global__ __launch_bounds__(512, 2) void gemm256_v9(
        const __hip_bfloat16* __restrict__ A,   // M x K
        const __hip_bfloat16* __restrict__ B,   // N x K
        float* __restrict__ C)                  // M x N
{
    __shared__ __align__(16) __hip_bfloat16 sA[2][256 * 64];
    __shared__ __align__(16) __hip_bfloat16 sB[2][256 * 64];

    const int tid  = threadIdx.x;
    const int lane = tid & 63;
    const int wid  = tid >> 6;
    const int wr   = wid >> 2;      // 0..1  (128-row half of A-tile)
    const int wc   = wid & 3;       // 0..3  (64-col slice of B-tile)
    const int l15  = lane & 15, l4 = lane >> 4;

    // XCD-aware bijective swizzle (nwg = 512, %8 == 0)
    const int bid = blockIdx.x;
    const int swz = (bid & 7) * 64 + (bid >> 3);
    const int m0  = (swz >> 4) * 256;   // 32 m-tiles
    const int n0  = (swz & 15) * 256;   // 16 n-tiles

    // staging geometry: row-in-group = tid>>3; 16B col-slot u = tid&7;
    // inverse-swizzled source col = (u ^ (row&7))*8
    const int rbase = tid >> 3;
    const int cs    = ((tid & 7) ^ (rbase & 7)) << 3;

    const __hip_bfloat16* Ab = A + (size_t)m0 * K_DIM;
    const __hip_bfloat16* Bb = B + (size_t)n0 * K_DIM;

    // acc quadrants: m 0..3 = mLo, 4..7 = mHi; n 0..1 = nLo, 2..3 = nHi
    f32x4 acc[8][4] = {};

    // ---- prologue (issue order matches steady state):
    //   tile0 full (8) ; B(1)g01 (2) ; A(1) full (4)
    STAGE_AG(0, 0, 0); STAGE_AG(0, 0, 1); STAGE_AG(0, 0, 2); STAGE_AG(0, 0, 3);
    STAGE_BG(0, 0, 0); STAGE_BG(0, 0, 1); STAGE_BG(0, 0, 2); STAGE_BG(0, 0, 3);
    STAGE_BG(1, 1, 0); STAGE_BG(1, 1, 1);
    STAGE_AG(1, 1, 0); STAGE_AG(1, 1, 1); STAGE_AG(1, 1, 2); STAGE_AG(1, 1, 3);
    VMCNT(6);          // tile 0 landed; {B(1)g01 x2, A(1) x4} in flight
    BAR();

    const int NT = K_DIM / 64;      // 64
    #pragma unroll 2
    for (int t = 0; t < NT; ++t) {
        const int c = t & 1;
        const __hip_bfloat16* TA = sA[c];
        const __hip_bfloat16* TB = sB[c];

        bf16x8 aLo[4][2], aHi[4][2], bLo[2][2], bHi[2][2];

        // ================= R0 =================
        #pragma unroll
        for (int n = 0; n < 2; ++n) bLo[n][0] = FRAG(TB, wc * 64 + n * 16 + l15, 0);
        #pragma unroll
        for (int m = 0; m < 4; ++m) aLo[m][0] = FRAG(TA, wr * 128 + m * 16 + l15, 0);
        #pragma unroll
        for (int n = 0; n < 2; ++n) bLo[n][1] = FRAG(TB, wc * 64 + n * 16 + l15, 1);
        #pragma unroll
        for (int m = 0; m < 4; ++m) aLo[m][1] = FRAG(TA, wr * 128 + m * 16 + l15, 1);
        #pragma unroll
        for (int n = 0; n < 2; ++n) {
            const int r = wc * 64 + 32 + n * 16 + l15;
            bHi[n][0] = FRAG(TB, r, 0);
            bHi[n][1] = FRAG(TB, r, 1);
        }
        __builtin_amdgcn_s_setprio(1);
        #pragma unroll
        for (int k = 0; k < 2; ++k)
            #pragma unroll
            for (int m = 0; m < 4; ++m)
                #pragma unroll
                for (int n = 0; n < 2; ++n)
                    acc[m][n] = __builtin_amdgcn_mfma_f32_16x16x32_bf16(
                                    aLo[m][k], bLo[n][k], acc[m][n], 0, 0, 0);
        __builtin_amdgcn_s_setprio(0);
        if (t + 1 < NT) { STAGE_BG(c ^ 1, t + 1, 2); STAGE_BG(c ^ 1, t + 1, 3); }
        BAR();   // BAR1: all B-reads (bLo,bHi) + aLo of buf c complete

        // ================= R1 =================
        if (t + 2 < NT) { STAGE_BG(c, t + 2, 0); STAGE_BG(c, t + 2, 1); }
        #pragma unroll
        for (int m = 0; m < 4; ++m) {
            const int r = wr * 128 + 64 + m * 16 + l15;
            aHi[m][0] = FRAG(TA, r, 0);
            aHi[m][1] = FRAG(TA, r, 1);
        }
        __builtin_amdgcn_s_setprio(1);
        #pragma unroll
        for (int k = 0; k < 2; ++k)
            #pragma unroll
            for (int m = 0; m < 4; ++m)
                #pragma unroll
                for (int n = 0; n < 2; ++n)
                    acc[m][2 + n] = __builtin_amdgcn_mfma_f32_16x16x32_bf16(
                                    aLo[m][k], bHi[n][k], acc[m][2 + n], 0, 0, 0);
        __builtin_amdgcn_s_setprio(0);
        BAR();   // BAR2: all A-reads (aLo,aHi) of buf c complete

        // ================= R2 =================
        if (t + 2 < NT) {
            STAGE_AG(c, t + 2, 0); STAGE_AG(c, t + 2, 1);
            STAGE_AG(c, t + 2, 2); STAGE_AG(c, t + 2, 3);
        }
        __builtin_amdgcn_s_setprio(1);
        #pragma unroll
        for (int k = 0; k < 2; ++k)
            #pragma unroll
            for (int m = 0; m < 4; ++m)
                #pragma unroll
                for (int n = 0; n < 2; ++n)
                    acc[4 + m][2 + n] = __builtin_amdgcn_mfma_f32_16x16x32_bf16(
                                    aHi[m][k], bHi[n][k], acc[4 + m][2 + n], 0, 0, 0);
        #pragma unroll
        for (int k = 0; k < 2; ++k)
            #pragma unroll
            for (int m = 0; m < 4; ++m)
                #pragma unroll
                for (int n = 0; n < 2; ++n)
                    acc[4 + m][n] = __builtin_amdgcn_mfma_f32_16x16x32_bf16(
                                    aHi[m][k], bLo[n][k], acc[4 + m][n], 0, 0, 0);
        __builtin_amdgcn_s_setprio(0);

        // ---------- K-tile boundary ----------
        if (t < NT - 2) {
            VMCNT(6);       // drains all of tile t+1; 6 loads of t+2 in flight
            BAR();
        } else if (t == NT - 2) {
            VMCNT(0);       // tail: drain B(NT-1)g23
            BAR();
        }
        // t == NT-1: registers only; fall through to epilogue
    }

    // ---- epilogue: ReLU + fp32 store ----
    const int row_base = m0 + wr * 128;
    const int col_base = n0 + wc * 64;
    #pragma unroll
    for (int m = 0; m < 8; ++m)
        #pragma unroll
        for (int n = 0; n < 4; ++n) {
            const f32x4 v = acc[m][n];
            const int col = col_base + n * 16 + l15;
            #pragma unroll
            for (int j = 0; j < 4; ++j) {
                const int row = row_base + m * 16 + l4 * 4 + j;
                C[(size_t)row * N_DIM + col] = fmaxf(v[j], 0.0f);
            }
        }
}

// ---------------------------------------------------------------------------
// fp32 fallback GEMM (only if ws_size < 160MB)
// ---------------------------------------------------------------------------
__global__ void gemm_f32_fallback(const float* __restrict__ A,
                                  const float* __restrict__ W,
                                  float* __restrict__ C) {
    __shared__ float As[64][17];
    __shared__ float Bs[64][17];
    const int tx = threadIdx.x & 15, ty = threadIdx.x >> 4;
    const int m0 = blockIdx.y * 64, n0 = blockIdx.x * 64;
    float acc[4][4] = {};
    for (int kt = 0; kt < K_DIM; kt += 16) {
        #pragma unroll
        for (int i = 0; i < 4; ++i) {
            int e = threadIdx.x + i * 256;
            int r = e >> 4, k = e & 15;
            As[r][k] = A[(size_t)(m0 + r) * K_DIM + kt + k];
            Bs[r][k] = W[(size_t)(n0 + r) * K_DIM + kt + k];
        }
        __syncthreads();
        #pragma unroll
        for (int k = 0; k < 16; ++k) {
            float av[4], bv[4];
            #pragma unroll
            for (int i = 0; i < 4; ++i) av[i] = As[ty * 4 + i][k];
            #pragma unroll
            for (int i = 0; i < 4; ++i) bv[i] = Bs[tx * 4 + i][k];
            #pragma unroll
            for (int i = 0; i < 4; ++i)
                #pragma unroll
                for (int j = 0; j < 4; ++j) acc[i][j] += av[i] * bv[j];
        }
        __syncthreads();
    }
    #pragma unroll
    for (int i = 0; i < 4; ++i)
        #pragma unroll
        for (int j = 0; j < 4; ++j)
            C[(size_t)(m0 + ty * 4 + i) * N_DIM + n0 + tx * 4 + j] =
                fmaxf(acc[i][j], 0.0f);
}

extern "C" void kernel_launch(void* const* d_in, const int* in_sizes, int n_in,
                              void* d_out, int out_size, void* d_ws, size_t ws_size,
                              hipStream_t stream) {
    const float* x       = (const float*)d_in[0];
    const int*   indices = (const int*)d_in[1];
    const float* values  = (const float*)d_in[2];
    float*       out     = (float*)d_out;

    float* Wf = (float*)((char*)d_ws + WF32_OFF);

    // 1. zero + scatter-build W (fp32, duplicates accumulate)
    hipMemsetAsync(Wf, 0, (size_t)N_DIM * K_DIM * sizeof(float), stream);
    scatter_kernel<<<(NNZ + 255) / 256, 256, 0, stream>>>(indices, values, Wf);

    if (ws_size >= WS_NEED) {
        unsigned short* Wb = (unsigned short*)((char*)d_ws + WBF16_OFF);
        unsigned short* xb = (unsigned short*)((char*)d_ws + XB_OFF);

        // 2. fused fp32 -> bf16 conversion (W then x), grid-stride @2048 blocks
        const int n4W = (N_DIM * K_DIM) / 4;
        const int n4T = n4W + (M_DIM * K_DIM) / 4;
        convert_both_kernel<<<2048, 256, 0, stream>>>(Wf, x, Wb, xb, n4W, n4T);

        // 3. 256^2 cluster-ahead bf16 MFMA GEMM + ReLU (session best)
        gemm256_v9<<<(M_DIM / 256) * (N_DIM / 256), 512, 0, stream>>>(
            (const __hip_bfloat16*)xb, (const __hip_bfloat16*)Wb, out);
    } else {
        gemm_f32_fallback<<<dim3(N_DIM / 64, M_DIM / 64), 256, 0, stream>>>(
            x, Wf, out);
    }
}